// Round 6
// baseline (698.384 us; speedup 1.0000x reference)
//
#include <hip/hip_runtime.h>
#include <math.h>

// B=4, T=1024, D=1024, H=16, DH=64, PD=4, DFF=4096
typedef __bf16 bf16;
typedef float f32x4 __attribute__((ext_vector_type(4)));
typedef bf16 bf16x8 __attribute__((ext_vector_type(8)));
typedef bf16 bf16x4 __attribute__((ext_vector_type(4)));

#define DEV __device__ __forceinline__

DEV f32x4 mfma16(bf16x8 a, bf16x8 b, f32x4 c) {
  return __builtin_amdgcn_mfma_f32_16x16x32_bf16(a, b, c, 0, 0, 0);
}

DEV float sigf(float x) { return 1.0f / (1.0f + __expf(-x)); }

// ---------------------------------------------------------------------------
// Fused fp32 -> bf16 weight cast (float4 vectorized). Element offsets:
//   qkv_w @0 | W4 stack @3145728 (w1w,w2w,w1r,w2r,memg,pad) | memv @3538944
//   out_w @4587520 | fc1 @5636096 | fc2 @9830400 | total 14024704
// ---------------------------------------------------------------------------
__global__ __launch_bounds__(256)
void cast_w_k(const float* __restrict__ qkv_w, const float* __restrict__ w1w,
              const float* __restrict__ w2w, const float* __restrict__ w1r,
              const float* __restrict__ w2r, const float* __restrict__ memg_w,
              const float* __restrict__ memv_w, const float* __restrict__ out_w,
              const float* __restrict__ fc1_w, const float* __restrict__ fc2_w,
              bf16* __restrict__ dst)
{
  const long i = ((long)blockIdx.x * 256 + threadIdx.x) * 4;
  if (i >= 14024704L) return;
  float4 v;
  if      (i < 3145728L)  v = *(const float4*)&qkv_w[i];
  else if (i < 3211264L)  v = *(const float4*)&w1w[i - 3145728L];
  else if (i < 3276800L)  v = *(const float4*)&w2w[i - 3211264L];
  else if (i < 3342336L)  v = *(const float4*)&w1r[i - 3276800L];
  else if (i < 3407872L)  v = *(const float4*)&w2r[i - 3342336L];
  else if (i < 3424256L)  v = *(const float4*)&memg_w[i - 3407872L];
  else if (i < 3538944L)  v = make_float4(0.f, 0.f, 0.f, 0.f);
  else if (i < 4587520L)  v = *(const float4*)&memv_w[i - 3538944L];
  else if (i < 5636096L)  v = *(const float4*)&out_w[i - 4587520L];
  else if (i < 9830400L)  v = *(const float4*)&fc1_w[i - 5636096L];
  else                    v = *(const float4*)&fc2_w[i - 9830400L];
  bf16x4 y;
  y[0] = (bf16)v.x; y[1] = (bf16)v.y; y[2] = (bf16)v.z; y[3] = (bf16)v.w;
  *(bf16x4*)&dst[i] = y;
}

// ---------------------------------------------------------------------------
// LayerNorm over D=1024, one block (256 thr) per row, writes bf16.
// ---------------------------------------------------------------------------
__global__ __launch_bounds__(256)
void ln_k(const float* __restrict__ x, const float* __restrict__ g,
          const float* __restrict__ bb, bf16* __restrict__ out)
{
  const int row = blockIdx.x, tid = threadIdx.x;
  const float4 xv = ((const float4*)(x + (long)row * 1024))[tid];
  float s  = xv.x + xv.y + xv.z + xv.w;
  float ss = xv.x * xv.x + xv.y * xv.y + xv.z * xv.z + xv.w * xv.w;
#pragma unroll
  for (int off = 1; off < 64; off <<= 1) {
    s  += __shfl_xor(s, off);
    ss += __shfl_xor(ss, off);
  }
  __shared__ float red[8];
  const int wave = tid >> 6, lane = tid & 63;
  if (lane == 0) { red[wave] = s; red[4 + wave] = ss; }
  __syncthreads();
  s  = red[0] + red[1] + red[2] + red[3];
  ss = red[4] + red[5] + red[6] + red[7];
  const float mu  = s * (1.0f / 1024.0f);
  const float var = ss * (1.0f / 1024.0f) - mu * mu;
  const float inv = rsqrtf(var + 1e-5f);
  const float4 gv = ((const float4*)g)[tid];
  const float4 bv = ((const float4*)bb)[tid];
  bf16x4 y;
  y[0] = (bf16)((xv.x - mu) * inv * gv.x + bv.x);
  y[1] = (bf16)((xv.y - mu) * inv * gv.y + bv.y);
  y[2] = (bf16)((xv.z - mu) * inv * gv.z + bv.z);
  y[3] = (bf16)((xv.w - mu) * inv * gv.w + bv.w);
  *(bf16x4*)&out[(long)row * 1024 + tid * 4] = y;
}

// ---------------------------------------------------------------------------
// Out-proj partial reduce + residual + LayerNorm2, one block per row.
// x2 = p0 + p1 + out_b + x ; h = LN(x2)*g+b (bf16)
// ---------------------------------------------------------------------------
__global__ __launch_bounds__(256)
void ln2red_k(const float* __restrict__ part, const float* __restrict__ out_b,
              const float* __restrict__ x, const float* __restrict__ g,
              const float* __restrict__ bb, float* __restrict__ x2,
              bf16* __restrict__ h)
{
  const int row = blockIdx.x, tid = threadIdx.x;
  const long idx = (long)row * 1024 + tid * 4;
  const float4 p0 = *(const float4*)&part[idx];
  const float4 p1 = *(const float4*)&part[idx + 4194304];
  const float4 xr = *(const float4*)&x[idx];
  const float4 ob = *(const float4*)&out_b[tid * 4];
  float4 xv;
  xv.x = p0.x + p1.x + xr.x + ob.x;
  xv.y = p0.y + p1.y + xr.y + ob.y;
  xv.z = p0.z + p1.z + xr.z + ob.z;
  xv.w = p0.w + p1.w + xr.w + ob.w;
  *(float4*)&x2[idx] = xv;
  float s  = xv.x + xv.y + xv.z + xv.w;
  float ss = xv.x * xv.x + xv.y * xv.y + xv.z * xv.z + xv.w * xv.w;
#pragma unroll
  for (int off = 1; off < 64; off <<= 1) {
    s  += __shfl_xor(s, off);
    ss += __shfl_xor(ss, off);
  }
  __shared__ float red[8];
  const int wave = tid >> 6, lane = tid & 63;
  if (lane == 0) { red[wave] = s; red[4 + wave] = ss; }
  __syncthreads();
  s  = red[0] + red[1] + red[2] + red[3];
  ss = red[4] + red[5] + red[6] + red[7];
  const float mu  = s * (1.0f / 1024.0f);
  const float var = ss * (1.0f / 1024.0f) - mu * mu;
  const float inv = rsqrtf(var + 1e-5f);
  const float4 gv = ((const float4*)g)[tid];
  const float4 bv = ((const float4*)bb)[tid];
  bf16x4 y;
  y[0] = (bf16)((xv.x - mu) * inv * gv.x + bv.x);
  y[1] = (bf16)((xv.y - mu) * inv * gv.y + bv.y);
  y[2] = (bf16)((xv.z - mu) * inv * gv.z + bv.z);
  y[3] = (bf16)((xv.w - mu) * inv * gv.w + bv.w);
  *(bf16x4*)&h[idx] = y;
}

// ---------------------------------------------------------------------------
// bf16 NT GEMM core, LDS-FREE: each wave loads its MFMA fragments directly
// from global into VGPRs (16B dwordx4 per lane; 16 rows x 64B = full cache
// lines). No __shared__, no __syncthreads -> compiler emits fine-grained
// vmcnt(N) and pipelines next-tile loads under current-tile MFMAs (explicit
// register prefetch below). A/B read 2x per block (wave-pair duplication);
// goes through L2 at ~34 TB/s, well under the old barrier-drain cost.
// ---------------------------------------------------------------------------
enum { M_BIAS_RES = 0, M_GELU = 1 };

#define GEMM_CORE(Aptr, Bptr, Kloop, Kstride)                                \
  const int tid = threadIdx.x;                                               \
  const int wave = tid >> 6, lane = tid & 63;                                \
  const int fr = lane & 15, fq = lane >> 4;                                  \
  const long bm = (long)blockIdx.y * 128;                                    \
  const long bn = (long)blockIdx.x * 128;                                    \
  const int wm = (wave >> 1) * 64, wn = (wave & 1) * 64;                     \
  const bf16* aP = Aptr + (bm + wm + fr) * (long)Kstride + fq * 8;           \
  const bf16* bP = Bptr + (bn + wn + fr) * (long)Kstride + fq * 8;           \
  f32x4 acc[4][4] = {};                                                      \
  bf16x8 af0[4], bf0[4];                                                     \
  _Pragma("unroll")                                                          \
  for (int i = 0; i < 4; ++i) {                                              \
    af0[i] = *(const bf16x8*)(aP + (long)i * 16 * Kstride);                  \
    bf0[i] = *(const bf16x8*)(bP + (long)i * 16 * Kstride);                  \
  }                                                                          \
  for (int kt = 0; kt < Kloop; kt += 32) {                                   \
    const int knx = (kt + 32 < Kloop) ? kt + 32 : kt;  /* clamp: safe */     \
    bf16x8 af1[4], bf1[4];                                                   \
    _Pragma("unroll")                                                        \
    for (int i = 0; i < 4; ++i) {                                            \
      af1[i] = *(const bf16x8*)(aP + (long)i * 16 * Kstride + knx);          \
      bf1[i] = *(const bf16x8*)(bP + (long)i * 16 * Kstride + knx);          \
    }                                                                        \
    _Pragma("unroll")                                                        \
    for (int i = 0; i < 4; ++i)                                              \
      _Pragma("unroll")                                                      \
      for (int j = 0; j < 4; ++j)                                            \
        acc[i][j] = mfma16(af0[i], bf0[j], acc[i][j]);                       \
    _Pragma("unroll")                                                        \
    for (int i = 0; i < 4; ++i) { af0[i] = af1[i]; bf0[i] = bf1[i]; }        \
  }

template <int MODE, int K>
__global__ __launch_bounds__(256)
void gemm_k(const bf16* __restrict__ A, const bf16* __restrict__ Bw,
            int N,
            const float* __restrict__ bias, const float* __restrict__ res,
            float* __restrict__ outf, bf16* __restrict__ outb)
{
  GEMM_CORE(A, Bw, K, K)
#pragma unroll
  for (int i = 0; i < 4; ++i) {
    const long row0 = bm + wm + i * 16 + fq * 4;
#pragma unroll
    for (int j = 0; j < 4; ++j) {
      const long col = bn + wn + j * 16 + fr;
#pragma unroll
      for (int r = 0; r < 4; ++r) {
        const long rr = row0 + r;
        float v = acc[i][j][r];
        if (MODE == M_BIAS_RES) {
          outf[rr * N + col] = v + bias[col] + res[rr * N + col];
        } else {  // M_GELU (exact, erf)
          v += bias[col];
          v = 0.5f * v * (1.0f + erff(v * 0.70710678118654752f));
          outb[rr * N + col] = (bf16)v;
        }
      }
    }
  }
}

// Split-K GEMM (N=1024 fixed): z covers K in [z*KLEN,(z+1)*KLEN).
template <int KLEN, int KSTRIDE>
__global__ __launch_bounds__(256)
void gemm_splitk_k(const bf16* __restrict__ A_, const bf16* __restrict__ Bw_,
                   float* __restrict__ part)
{
  const bf16* A  = A_  + (long)blockIdx.z * KLEN;
  const bf16* Bw = Bw_ + (long)blockIdx.z * KLEN;
  float* outf = part + (long)blockIdx.z * 4194304;
  GEMM_CORE(A, Bw, KLEN, KSTRIDE)
#pragma unroll
  for (int i = 0; i < 4; ++i) {
    const long row0 = bm + wm + i * 16 + fq * 4;
#pragma unroll
    for (int j = 0; j < 4; ++j) {
      const long col = bn + wn + j * 16 + fr;
#pragma unroll
      for (int r = 0; r < 4; ++r)
        outf[(row0 + r) * 1024 + col] = acc[i][j][r];
    }
  }
}

// d_out = part0 + part1 + fc2_b + x2   (one block per token row)
__global__ __launch_bounds__(256)
void fc2red_k(const float* __restrict__ part, const float* __restrict__ x2,
              const float* __restrict__ fc2_b, float* __restrict__ out)
{
  const long row = blockIdx.x;
  const int tid = threadIdx.x;
  const long idx = row * 1024 + tid * 4;
  const float4 p0 = *(const float4*)&part[idx];
  const float4 p1 = *(const float4*)&part[idx + 4194304];
  const float4 xv = *(const float4*)&x2[idx];
  const float4 bv = *(const float4*)&fc2_b[tid * 4];
  float4 o;
  o.x = p0.x + p1.x + xv.x + bv.x;
  o.y = p0.y + p1.y + xv.y + bv.y;
  o.z = p0.z + p1.z + xv.z + bv.z;
  o.w = p0.w + p1.w + xv.w + bv.w;
  *(float4*)&out[idx] = o;
}

// Fused h-projections: N=4480 stacked [qkv(3072) | w4(384) | memv(1024)].
// q scaled by DH^-0.5; v written TRANSPOSED [B,H,DH,T].
__global__ __launch_bounds__(256)
void gemm3_k(const bf16* __restrict__ A, const bf16* __restrict__ Bw,
             const float* __restrict__ qkv_b, const float* __restrict__ memv_b,
             bf16* __restrict__ qk_out /*q|k at [B,H,T,64]*/,
             bf16* __restrict__ vt_out /*[B,H,64,T]*/,
             float* __restrict__ w4out /*[4096,384]*/,
             float* __restrict__ memval /*[B,T,D]*/)
{
  GEMM_CORE(A, Bw, 1024, 1024)
  if (bn < 3072) {
#pragma unroll
    for (int i = 0; i < 4; ++i) {
      const long row0 = bm + wm + i * 16 + fq * 4;
      const long b = row0 >> 10, t0 = row0 & 1023;
#pragma unroll
      for (int j = 0; j < 4; ++j) {
        const long col = bn + wn + j * 16 + fr;
        const long i3 = col >> 10;          // 0=q 1=k 2=v (uniform per j)
        const long hh = (col >> 6) & 15;
        const long d  = col & 63;
        const float bs = qkv_b[col];
        if (i3 == 2) {                      // v -> transposed, vectorize over t
          bf16x4 y;
#pragma unroll
          for (int r = 0; r < 4; ++r) y[r] = (bf16)(acc[i][j][r] + bs);
          *(bf16x4*)&vt_out[((b * 16 + hh) * 64 + d) * 1024 + t0] = y;
        } else {
          const float sc2 = (i3 == 0) ? 0.125f : 1.0f;
          const long base = i3 * 4194304 + ((b * 16 + hh) * 1024 + t0) * 64 + d;
#pragma unroll
          for (int r = 0; r < 4; ++r)
            qk_out[base + r * 64] = (bf16)((acc[i][j][r] + bs) * sc2);
        }
      }
    }
  } else if (bn < 3456) {
#pragma unroll
    for (int i = 0; i < 4; ++i) {
      const long row0 = bm + wm + i * 16 + fq * 4;
#pragma unroll
      for (int j = 0; j < 4; ++j) {
        const long col = bn + wn + j * 16 + fr - 3072;
#pragma unroll
        for (int r = 0; r < 4; ++r)
          w4out[(row0 + r) * 384 + col] = acc[i][j][r];
      }
    }
  } else {
#pragma unroll
    for (int i = 0; i < 4; ++i) {
      const long row0 = bm + wm + i * 16 + fq * 4;
#pragma unroll
      for (int j = 0; j < 4; ++j) {
        const long col = bn + wn + j * 16 + fr - 3456;
        const float bs = memv_b[col];
#pragma unroll
        for (int r = 0; r < 4; ++r)
          memval[(row0 + r) * 1024 + col] = acc[i][j][r] + bs;
      }
    }
  }
}

// ---------------------------------------------------------------------------
// Flash-style causal attention + fused memory-branch combine. Block bx
// handles q-tiles {bx, 15-bx} -> every block does 17 k-tile iterations.
// Epilogue: comb = bf16(softmax(QK)V + g * memval), g precomputed per row.
// ---------------------------------------------------------------------------
__global__ __launch_bounds__(256, 3)
void attn_k(const bf16* __restrict__ q, const bf16* __restrict__ k,
            const bf16* __restrict__ vt, const float* __restrict__ memval,
            const float* __restrict__ gbuf, bf16* __restrict__ comb)
{
  __shared__ __align__(16) bf16 Ks[64 * 72];
  __shared__ __align__(16) bf16 Vs[64 * 72];
  __shared__ __align__(16) bf16 Ps[4][16 * 72];
  const int bx = blockIdx.x, h = blockIdx.y, b = blockIdx.z;
  const int tid = threadIdx.x;
  const int wave = tid >> 6, lane = tid & 63;
  const int fr = lane & 15, fq = lane >> 4;
  const long bh  = ((long)b * 16 + h) * 1024;   // q/k row base
  const long bhv = ((long)b * 16 + h) * 64;     // vt row base

  for (int pass = 0; pass < 2; ++pass) {
    const int qt = pass ? 15 - bx : bx;
    const int qbase = qt * 64;
    const bf16x8 aq0 = *(const bf16x8*)&q[(bh + qbase + wave * 16 + fr) * 64 + fq * 8];
    const bf16x8 aq1 = *(const bf16x8*)&q[(bh + qbase + wave * 16 + fr) * 64 + 32 + fq * 8];

    f32x4 o[4] = {};
    float m_r[4] = {-1e30f, -1e30f, -1e30f, -1e30f};
    float l_r[4] = {0.0f, 0.0f, 0.0f, 0.0f};

    for (int kt = 0; kt <= qt; ++kt) {
      const int kb = kt * 64;
      __syncthreads();                           // protect LDS reuse
#pragma unroll
      for (int rep = 0; rep < 2; ++rep) {        // stage K tile
        const int c = rep * 256 + tid;           // 512 x 16B chunks
        const int key = c >> 3, seg = c & 7;
        *(bf16x8*)&Ks[key * 72 + seg * 8] =
            *(const bf16x8*)&k[(bh + kb + key) * 64 + seg * 8];
      }
#pragma unroll
      for (int rep = 0; rep < 2; ++rep) {        // stage V^T tile (row d)
        const int c = rep * 256 + tid;
        const int d = c >> 3, seg = c & 7;
        *(bf16x8*)&Vs[d * 72 + seg * 8] =
            *(const bf16x8*)&vt[(bhv + d) * 1024 + kb + seg * 8];
      }
      __syncthreads();

      // S = Q K^T (16 q-rows per wave x 64 keys)
      f32x4 s[4];
#pragma unroll
      for (int j = 0; j < 4; ++j) {
        const bf16x8 b0 = *(const bf16x8*)&Ks[(j * 16 + fr) * 72 + fq * 8];
        const bf16x8 b1 = *(const bf16x8*)&Ks[(j * 16 + fr) * 72 + 32 + fq * 8];
        f32x4 tacc = {};
        tacc = mfma16(aq0, b0, tacc);
        tacc = mfma16(aq1, b1, tacc);
        s[j] = tacc;
      }
      if (kt == qt) {                            // causal mask, diagonal tile
#pragma unroll
        for (int j = 0; j < 4; ++j)
#pragma unroll
          for (int r = 0; r < 4; ++r)
            if (kb + j * 16 + fr > qbase + wave * 16 + fq * 4 + r) s[j][r] = -1e30f;
      }

      // online softmax per q-row (rows live on 16-lane groups)
      float alpha[4];
#pragma unroll
      for (int r = 0; r < 4; ++r) {
        float t = fmaxf(fmaxf(s[0][r], s[1][r]), fmaxf(s[2][r], s[3][r]));
#pragma unroll
        for (int off = 1; off < 16; off <<= 1) t = fmaxf(t, __shfl_xor(t, off));
        const float mn = fmaxf(m_r[r], t);
        alpha[r] = __expf(m_r[r] - mn);
        m_r[r] = mn;
        float ls = 0.0f;
#pragma unroll
        for (int j = 0; j < 4; ++j) {
          const float p = __expf(s[j][r] - mn);
          s[j][r] = p;
          ls += p;
        }
#pragma unroll
        for (int off = 1; off < 16; off <<= 1) ls += __shfl_xor(ls, off);
        l_r[r] = l_r[r] * alpha[r] + ls;
#pragma unroll
        for (int jd = 0; jd < 4; ++jd) o[jd][r] *= alpha[r];
      }

      // P: C/D layout -> A-operand layout via per-wave LDS
#pragma unroll
      for (int j = 0; j < 4; ++j)
#pragma unroll
        for (int r = 0; r < 4; ++r)
          Ps[wave][(fq * 4 + r) * 72 + j * 16 + fr] = (bf16)s[j][r];

      const bf16x8 ap0 = *(const bf16x8*)&Ps[wave][fr * 72 + fq * 8];
      const bf16x8 ap1 = *(const bf16x8*)&Ps[wave][fr * 72 + 32 + fq * 8];
#pragma unroll
      for (int jd = 0; jd < 4; ++jd) {
        const bf16x8 b0 = *(const bf16x8*)&Vs[(jd * 16 + fr) * 72 + fq * 8];
        const bf16x8 b1 = *(const bf16x8*)&Vs[(jd * 16 + fr) * 72 + 32 + fq * 8];
        o[jd] = mfma16(ap0, b0, o[jd]);
        o[jd] = mfma16(ap1, b1, o[jd]);
      }
    }

#pragma unroll
    for (int r = 0; r < 4; ++r) {
      const long t_ = qbase + wave * 16 + fq * 4 + r;
      const long row = (long)b * 1024 + t_;
      const float inv = 1.0f / l_r[r];
      const float gv = gbuf[row];
#pragma unroll
      for (int jd = 0; jd < 4; ++jd) {
        const long col = h * 64 + jd * 16 + fr;
        comb[row * 1024 + col] =
            (bf16)(o[jd][r] * inv + gv * memval[row * 1024 + col]);
      }
    }
  }
}

// ---------------------------------------------------------------------------
// Plücker exterior (used inline by memscore).
// ---------------------------------------------------------------------------
DEV void ext6(const float* p1, const float* p2, float* out) {
  const float L0 = p1[0] * p2[1] - p1[1] * p2[0];
  const float L1 = p1[0] * p2[2] - p1[2] * p2[0];
  const float L2 = p1[0] * p2[3] - p1[3] * p2[0];
  const float L3 = p1[1] * p2[2] - p1[2] * p2[1];
  const float L4 = p1[1] * p2[3] - p1[3] * p2[1];
  const float L5 = p1[2] * p2[3] - p1[3] * p2[2];
  const float nrm = sqrtf(L0*L0 + L1*L1 + L2*L2 + L3*L3 + L4*L4 + L5*L5);
  const float inv = 1.0f / fmaxf(nrm, 1e-12f);
  out[0] = L0 * inv; out[1] = L1 * inv; out[2] = L2 * inv;
  out[3] = L3 * inv; out[4] = L4 * inv; out[5] = L5 * inv;
}

// ---------------------------------------------------------------------------
// mem_score[b,h,i] = sum_{j<i} |dot6(rl_i, jw_j)| * d^(i-j), chunked over j.
// Lines computed INLINE from w4out. Grid (10,64): lower-triangle
// (i-tile, j-chunk) pairs; atomicAdd partials into pre-zeroed ms.
// ---------------------------------------------------------------------------
__global__ __launch_bounds__(256)
void memscore_k(const float* __restrict__ w4o,
                const float* __restrict__ decay_logits, float* __restrict__ ms)
{
  __shared__ __align__(16) float jwS[256 * 8];
  const int IT[10] = {0,1,1,2,2,2,3,3,3,3};
  const int JC[10] = {0,0,1,0,1,2,0,1,2,3};
  const int it = IT[blockIdx.x], jc = JC[blockIdx.x];
  const int bh = blockIdx.y, hh = bh & 15, b = bh >> 4;
  const float d = sigf(decay_logits[hh]);
  const float invd = 1.0f / d;
  const int j0 = jc * 256;
  {  // stage jw rows [j0, j0+256): write line = J6 * ext(w1_prev, w2_cur)
    const int j = j0 + threadIdx.x;
    const long nj = (long)b * 1024 + j;
    float p1[4], p2[4], wl[6];
    if (j == 0) { p1[0] = p1[1] = p1[2] = p1[3] = 0.0f; }
    else {
      const float* s = w4o + (nj - 1) * 384 + hh * 4;
      p1[0] = s[0]; p1[1] = s[1]; p1[2] = s[2]; p1[3] = s[3];
    }
    { const float* s = w4o + nj * 384 + 64 + hh * 4;
      p2[0] = s[0]; p2[1] = s[1]; p2[2] = s[2]; p2[3] = s[3]; }
    ext6(p1, p2, wl);
    float* dstS = &jwS[threadIdx.x * 8];
    dstS[0] =  wl[5]; dstS[1] = -wl[4]; dstS[2] =  wl[3];
    dstS[3] =  wl[2]; dstS[4] = -wl[1]; dstS[5] =  wl[0];
    dstS[6] = 0.0f;   dstS[7] = 0.0f;
  }
  __syncthreads();
  const int i = it * 256 + threadIdx.x;
  const long ni = (long)b * 1024 + i;
  float q1[4], q2[4], rv[6];
  { const float* s = w4o + ni * 384 + 128 + hh * 4;
    q1[0] = s[0]; q1[1] = s[1]; q1[2] = s[2]; q1[3] = s[3]; }
  { const float* s = w4o + ni * 384 + 192 + hh * 4;
    q2[0] = s[0]; q2[1] = s[1]; q2[2] = s[2]; q2[3] = s[3]; }
  ext6(q1, q2, rv);
  const int nj = (jc == it) ? (int)threadIdx.x : 256;   // j < i
  float w = __expf(__logf(d) * (float)(i - j0));        // d^(i-j0)
  float s = 0.0f;
  for (int jj = 0; jj < nj; ++jj) {
    const float* row = &jwS[jj * 8];
    const float dot = rv[0] * row[0] + rv[1] * row[1] + rv[2] * row[2] +
                      rv[3] * row[3] + rv[4] * row[4] + rv[5] * row[5];
    s += fabsf(dot) * w;
    w *= invd;
  }
  atomicAdd(&ms[(long)bh * 1024 + i], s);
}

// ---------------------------------------------------------------------------
// g[b,t] = mean_h sigmoid(ms*scale) * sigmoid(memg + memg_b)
// ---------------------------------------------------------------------------
__global__ __launch_bounds__(256)
void gate_k(const float* __restrict__ w4o, const float* __restrict__ ms,
            const float* __restrict__ memg_b, const float* __restrict__ mem_scale,
            float* __restrict__ g)
{
  const int n = blockIdx.x * 256 + threadIdx.x;   // b*1024 + t
  const int b = n >> 10, t = n & 1023;
  float acc = 0.0f;
#pragma unroll
  for (int h = 0; h < 16; ++h) {
    const float gate = sigf(w4o[(long)n * 384 + 256 + h] + memg_b[h]);
    acc += sigf(ms[((long)(b * 16 + h)) * 1024 + t] * mem_scale[h]) * gate;
  }
  g[n] = acc * (1.0f / 16.0f);
}

// ---------------------------------------------------------------------------
extern "C" void kernel_launch(void* const* d_in, const int* in_sizes, int n_in,
                              void* d_out, int out_size, void* d_ws, size_t ws_size,
                              hipStream_t stream) {
  (void)in_sizes; (void)n_in; (void)out_size; (void)ws_size;
  const float* x         = (const float*)d_in[0];
  const float* ln1_g     = (const float*)d_in[1];
  const float* ln1_b     = (const float*)d_in[2];
  const float* qkv_w     = (const float*)d_in[3];
  const float* qkv_b     = (const float*)d_in[4];
  const float* w1w       = (const float*)d_in[5];
  const float* w2w       = (const float*)d_in[6];
  const float* w1r       = (const float*)d_in[7];
  const float* w2r       = (const float*)d_in[8];
  const float* memv_w    = (const float*)d_in[9];
  const float* memv_b    = (const float*)d_in[10];
  const float* memg_w    = (const float*)d_in[11];
  const float* memg_b    = (const float*)d_in[12];
  const float* mem_scale = (const float*)d_in[13];
  const float* out_w     = (const float*)d_in[14];
  const float* out_b     = (const float*)d_in[15];
  const float* decay_l   = (const float*)d_in[16];
  const float* ln2_g     = (const float*)d_in[17];
  const float* ln2_b     = (const float*)d_in[18];
  const float* fc1_w     = (const float*)d_in[19];
  const float* fc1_b     = (const float*)d_in[20];
  const float* fc2_w     = (const float*)d_in[21];
  const float* fc2_b     = (const float*)d_in[22];

  char* ws = (char*)d_ws;
  bf16*  Wbf    = (bf16*)ws;                       // stacked bf16 weights (28 MB)
  bf16*  Wout   = Wbf + 4587520;
  bf16*  Wfc1   = Wbf + 5636096;
  bf16*  Wfc2   = Wbf + 9830400;
  bf16*  h_bf   = (bf16*)(ws + 28049408);          // 8 MB (h, then h2)
  bf16*  q_bf   = (bf16*)(ws + 36438016);          // q|k|vt, 8 MB each
  bf16*  vt_bf  = q_bf + 2 * 4194304;
  // outproj partials (2x16 MB) overlay dead q/k/vt after attention
  float* oppart = (float*)(ws + 36438016);
  bf16*  fc1out = q_bf;                            // 32 MB, after ln2red
  float* w4out  = (float*)(ws + 78381056);         // [4096,384] f32 (6.3 MB)
  float* msb    = (float*)(ws + 84672512);         // [64,1024] f32
  float* gbuf   = (float*)(ws + 84934656);         // [4096] f32
  float* memval = (float*)(ws + 88080384);         // 16 MB
  // FC2 partials (2x16 MB) overlay dead w4out..memval region
  float* fc2part = (float*)(ws + 69992448);        // 69992448..103546880
  bf16*  comb   = (bf16*)(ws + 104857600);         // 8 MB
  float* x2     = (float*)(ws + 113246208);        // 16 MB

  // 1) weight cast (vectorized x4)
  cast_w_k<<<13696, 256, 0, stream>>>(qkv_w, w1w, w2w, w1r, w2r, memg_w,
                                      memv_w, out_w, fc1_w, fc2_w, Wbf);
  // 2) LN1
  ln_k<<<4096, 256, 0, stream>>>(x, ln1_g, ln1_b, h_bf);
  // 3) fused QKV + W4 + memv GEMM (N=4480)
  gemm3_k<<<dim3(35, 32), 256, 0, stream>>>(h_bf, Wbf, qkv_b, memv_b,
                                            q_bf, vt_bf, w4out, memval);
  // 4) incidence x decay reduction (lines inlined; chunked + atomic)
  hipMemsetAsync(msb, 0, 64 * 1024 * sizeof(float), stream);
  memscore_k<<<dim3(10, 64), 256, 0, stream>>>(w4out, decay_l, msb);
  // 5) per-row gate mean
  gate_k<<<16, 256, 0, stream>>>(w4out, msb, memg_b, mem_scale, gbuf);
  // 6) causal attention + fused combine -> comb (bf16)
  attn_k<<<dim3(8, 16, 4), 256, 0, stream>>>(q_bf, q_bf + 4194304, vt_bf,
                                             memval, gbuf, comb);
  // 7) out-proj split-K=2 -> partials (q/k/vt dead)
  gemm_splitk_k<512, 1024><<<dim3(8, 32, 2), 256, 0, stream>>>(comb, Wout,
                                                               oppart);
  // 8) reduce + bias + residual(x) -> x2, then LN2 -> h_bf
  ln2red_k<<<4096, 256, 0, stream>>>(oppart, out_b, x, ln2_g, ln2_b, x2, h_bf);
  // 9) FC1 + GELU(exact)  (overwrites oppart region)
  gemm_k<M_GELU, 1024><<<dim3(32, 32), 256, 0, stream>>>(h_bf, Wfc1, 4096,
                                                   fc1_b, nullptr, nullptr, fc1out);
  // 10) FC2 split-K=2 -> partials
  gemm_splitk_k<2048, 4096><<<dim3(8, 32, 2), 256, 0, stream>>>(fc1out, Wfc2,
                                                                fc2part);
  // 11) reduce partials + bias + residual(x2) -> d_out
  fc2red_k<<<4096, 256, 0, stream>>>(fc2part, x2, fc2_b, (float*)d_out);
}

// Round 8
// 432.800 us; speedup vs baseline: 1.6136x; 1.6136x over previous
//
#include <hip/hip_runtime.h>
#include <math.h>

// B=4, T=1024, D=1024, H=16, DH=64, PD=4, DFF=4096
typedef __bf16 bf16;
typedef float f32x4 __attribute__((ext_vector_type(4)));
typedef bf16 bf16x8 __attribute__((ext_vector_type(8)));
typedef bf16 bf16x4 __attribute__((ext_vector_type(4)));

#define DEV __device__ __forceinline__

DEV void async16(const void* g, void* s) {
  __builtin_amdgcn_global_load_lds(
      (const __attribute__((address_space(1))) unsigned int*)g,
      (__attribute__((address_space(3))) unsigned int*)s, 16, 0, 0);
}

DEV f32x4 mfma16(bf16x8 a, bf16x8 b, f32x4 c) {
  return __builtin_amdgcn_mfma_f32_16x16x32_bf16(a, b, c, 0, 0, 0);
}

DEV float sigf(float x) { return 1.0f / (1.0f + __expf(-x)); }

// ---------------------------------------------------------------------------
// Fused fp32 -> bf16 weight cast (float4 vectorized). Element offsets:
//   qkv_w @0 | W4 stack @3145728 (w1w,w2w,w1r,w2r,memg,pad) | memv @3538944
//   out_w @4587520 | fc1 @5636096 | fc2 @9830400 | total 14024704
// ---------------------------------------------------------------------------
__global__ __launch_bounds__(256)
void cast_w_k(const float* __restrict__ qkv_w, const float* __restrict__ w1w,
              const float* __restrict__ w2w, const float* __restrict__ w1r,
              const float* __restrict__ w2r, const float* __restrict__ memg_w,
              const float* __restrict__ memv_w, const float* __restrict__ out_w,
              const float* __restrict__ fc1_w, const float* __restrict__ fc2_w,
              bf16* __restrict__ dst)
{
  const long i = ((long)blockIdx.x * 256 + threadIdx.x) * 4;
  if (i >= 14024704L) return;
  float4 v;
  if      (i < 3145728L)  v = *(const float4*)&qkv_w[i];
  else if (i < 3211264L)  v = *(const float4*)&w1w[i - 3145728L];
  else if (i < 3276800L)  v = *(const float4*)&w2w[i - 3211264L];
  else if (i < 3342336L)  v = *(const float4*)&w1r[i - 3276800L];
  else if (i < 3407872L)  v = *(const float4*)&w2r[i - 3342336L];
  else if (i < 3424256L)  v = *(const float4*)&memg_w[i - 3407872L];
  else if (i < 3538944L)  v = make_float4(0.f, 0.f, 0.f, 0.f);
  else if (i < 4587520L)  v = *(const float4*)&memv_w[i - 3538944L];
  else if (i < 5636096L)  v = *(const float4*)&out_w[i - 4587520L];
  else if (i < 9830400L)  v = *(const float4*)&fc1_w[i - 5636096L];
  else                    v = *(const float4*)&fc2_w[i - 9830400L];
  bf16x4 y;
  y[0] = (bf16)v.x; y[1] = (bf16)v.y; y[2] = (bf16)v.z; y[3] = (bf16)v.w;
  *(bf16x4*)&dst[i] = y;
}

// ---------------------------------------------------------------------------
// LayerNorm over D=1024, one block (256 thr) per row, writes bf16.
// ---------------------------------------------------------------------------
__global__ __launch_bounds__(256)
void ln_k(const float* __restrict__ x, const float* __restrict__ g,
          const float* __restrict__ bb, bf16* __restrict__ out)
{
  const int row = blockIdx.x, tid = threadIdx.x;
  const float4 xv = ((const float4*)(x + (long)row * 1024))[tid];
  float s  = xv.x + xv.y + xv.z + xv.w;
  float ss = xv.x * xv.x + xv.y * xv.y + xv.z * xv.z + xv.w * xv.w;
#pragma unroll
  for (int off = 1; off < 64; off <<= 1) {
    s  += __shfl_xor(s, off);
    ss += __shfl_xor(ss, off);
  }
  __shared__ float red[8];
  const int wave = tid >> 6, lane = tid & 63;
  if (lane == 0) { red[wave] = s; red[4 + wave] = ss; }
  __syncthreads();
  s  = red[0] + red[1] + red[2] + red[3];
  ss = red[4] + red[5] + red[6] + red[7];
  const float mu  = s * (1.0f / 1024.0f);
  const float var = ss * (1.0f / 1024.0f) - mu * mu;
  const float inv = rsqrtf(var + 1e-5f);
  const float4 gv = ((const float4*)g)[tid];
  const float4 bv = ((const float4*)bb)[tid];
  bf16x4 y;
  y[0] = (bf16)((xv.x - mu) * inv * gv.x + bv.x);
  y[1] = (bf16)((xv.y - mu) * inv * gv.y + bv.y);
  y[2] = (bf16)((xv.z - mu) * inv * gv.z + bv.z);
  y[3] = (bf16)((xv.w - mu) * inv * gv.w + bv.w);
  *(bf16x4*)&out[(long)row * 1024 + tid * 4] = y;
}

// ---------------------------------------------------------------------------
// Out-proj partial reduce + residual + LayerNorm2, one block per row.
// x2 = p0 + p1 + out_b + x ; h = LN(x2)*g+b (bf16)
// ---------------------------------------------------------------------------
__global__ __launch_bounds__(256)
void ln2red_k(const float* __restrict__ part, const float* __restrict__ out_b,
              const float* __restrict__ x, const float* __restrict__ g,
              const float* __restrict__ bb, float* __restrict__ x2,
              bf16* __restrict__ h)
{
  const int row = blockIdx.x, tid = threadIdx.x;
  const long idx = (long)row * 1024 + tid * 4;
  const float4 p0 = *(const float4*)&part[idx];
  const float4 p1 = *(const float4*)&part[idx + 4194304];
  const float4 xr = *(const float4*)&x[idx];
  const float4 ob = *(const float4*)&out_b[tid * 4];
  float4 xv;
  xv.x = p0.x + p1.x + xr.x + ob.x;
  xv.y = p0.y + p1.y + xr.y + ob.y;
  xv.z = p0.z + p1.z + xr.z + ob.z;
  xv.w = p0.w + p1.w + xr.w + ob.w;
  *(float4*)&x2[idx] = xv;
  float s  = xv.x + xv.y + xv.z + xv.w;
  float ss = xv.x * xv.x + xv.y * xv.y + xv.z * xv.z + xv.w * xv.w;
#pragma unroll
  for (int off = 1; off < 64; off <<= 1) {
    s  += __shfl_xor(s, off);
    ss += __shfl_xor(ss, off);
  }
  __shared__ float red[8];
  const int wave = tid >> 6, lane = tid & 63;
  if (lane == 0) { red[wave] = s; red[4 + wave] = ss; }
  __syncthreads();
  s  = red[0] + red[1] + red[2] + red[3];
  ss = red[4] + red[5] + red[6] + red[7];
  const float mu  = s * (1.0f / 1024.0f);
  const float var = ss * (1.0f / 1024.0f) - mu * mu;
  const float inv = rsqrtf(var + 1e-5f);
  const float4 gv = ((const float4*)g)[tid];
  const float4 bv = ((const float4*)bb)[tid];
  bf16x4 y;
  y[0] = (bf16)((xv.x - mu) * inv * gv.x + bv.x);
  y[1] = (bf16)((xv.y - mu) * inv * gv.y + bv.y);
  y[2] = (bf16)((xv.z - mu) * inv * gv.z + bv.z);
  y[3] = (bf16)((xv.w - mu) * inv * gv.w + bv.w);
  *(bf16x4*)&h[idx] = y;
}

// ---------------------------------------------------------------------------
// bf16 NT GEMM core (round-4 m97 structure, best measured): 128x128 tile,
// BK=32, 256 thr, global_load_lds staging, 2 barriers/iter. BMT/BNT are
// block-tile indices supplied by the caller (L2-locality swizzled).
// ---------------------------------------------------------------------------
enum { M_BIAS_RES = 0, M_GELU = 1 };

#define GEMM_CORE(Aptr, Bptr, Kloop, Kstride, BMT, BNT)                      \
  __shared__ __align__(16) bf16 As[128 * 32];                                \
  __shared__ __align__(16) bf16 Bs[128 * 32];                                \
  const int tid = threadIdx.x;                                               \
  const int wave = tid >> 6, lane = tid & 63;                                \
  const int fr = lane & 15, fq = lane >> 4;                                  \
  const long bm = (long)(BMT) * 128;                                         \
  const long bn = (long)(BNT) * 128;                                         \
  const int wm = (wave >> 1) * 64, wn = (wave & 1) * 64;                     \
  const int sr = wave * 16 + (lane >> 2);                                    \
  const int sc = (lane & 3) * 8;                                             \
  const bf16* ag0 = Aptr + (bm + sr) * (long)Kstride + sc;                   \
  const bf16* ag1 = Aptr + (bm + 64 + sr) * (long)Kstride + sc;              \
  const bf16* bg0 = Bptr + (bn + sr) * (long)Kstride + sc;                   \
  const bf16* bg1 = Bptr + (bn + 64 + sr) * (long)Kstride + sc;              \
  bf16* as0 = &As[(wave * 16) * 32];                                         \
  bf16* as1 = &As[(64 + wave * 16) * 32];                                    \
  bf16* bs0 = &Bs[(wave * 16) * 32];                                         \
  bf16* bs1 = &Bs[(64 + wave * 16) * 32];                                    \
  f32x4 acc[4][4] = {};                                                      \
  for (int kt = 0; kt < Kloop; kt += 32) {                                   \
    __syncthreads();                                                         \
    async16(ag0 + kt, as0);                                                  \
    async16(ag1 + kt, as1);                                                  \
    async16(bg0 + kt, bs0);                                                  \
    async16(bg1 + kt, bs1);                                                  \
    __syncthreads();                                                         \
    bf16x8 af[4], bfr[4];                                                    \
    _Pragma("unroll")                                                        \
    for (int i = 0; i < 4; ++i)                                              \
      af[i] = *(const bf16x8*)&As[(wm + i * 16 + fr) * 32 + fq * 8];         \
    _Pragma("unroll")                                                        \
    for (int j = 0; j < 4; ++j)                                              \
      bfr[j] = *(const bf16x8*)&Bs[(wn + j * 16 + fr) * 32 + fq * 8];        \
    _Pragma("unroll")                                                        \
    for (int i = 0; i < 4; ++i)                                              \
      _Pragma("unroll")                                                      \
      for (int j = 0; j < 4; ++j)                                            \
        acc[i][j] = mfma16(af[i], bfr[j], acc[i][j]);                        \
  }

// FC1 (+GELU epilogue). Grid (32,32). Swizzle: groups of 8 bn-tiles x all 32
// bm-tiles -> blocks dispatched near in time share a 1 MB B-panel + sweep A
// once per group (demand: A 4x8MB + B 8MB vs unswizzled A 32x8MB).
template <int MODE, int K>
__global__ __launch_bounds__(256, 4)
void gemm_k(const bf16* __restrict__ A, const bf16* __restrict__ Bw,
            int N,
            const float* __restrict__ bias, const float* __restrict__ res,
            float* __restrict__ outf, bf16* __restrict__ outb)
{
  const int f = blockIdx.x + gridDim.x * blockIdx.y;   // 0..1023
  const int grp = f >> 8, r = f & 255;                 // 8 bn x 32 bm groups
  const int bnt = grp * 8 + (r & 7), bmt = r >> 3;
  GEMM_CORE(A, Bw, K, K, bmt, bnt)
#pragma unroll
  for (int i = 0; i < 4; ++i) {
    const long row0 = bm + wm + i * 16 + fq * 4;
#pragma unroll
    for (int j = 0; j < 4; ++j) {
      const long col = bn + wn + j * 16 + fr;
#pragma unroll
      for (int r2 = 0; r2 < 4; ++r2) {
        const long rr = row0 + r2;
        float v = acc[i][j][r2];
        if (MODE == M_BIAS_RES) {
          outf[rr * N + col] = v + bias[col] + res[rr * N + col];
        } else {  // M_GELU (exact, erf)
          v += bias[col];
          v = 0.5f * v * (1.0f + erff(v * 0.70710678118654752f));
          outb[rr * N + col] = (bf16)v;
        }
      }
    }
  }
}

// Split-K GEMM (N=1024 fixed): z covers K in [z*KLEN,(z+1)*KLEN).
// Grid (8,32,2). Swizzle: supertiles of 8 bn x 4 bm (32 blocks) -> each
// supertile touches all of B (cached) + 4 A-panels; B demand 8x8MB -> ~8MB.
template <int KLEN, int KSTRIDE>
__global__ __launch_bounds__(256, 4)
void gemm_splitk_k(const bf16* __restrict__ A_, const bf16* __restrict__ Bw_,
                   float* __restrict__ part)
{
  const bf16* A  = A_  + (long)blockIdx.z * KLEN;
  const bf16* Bw = Bw_ + (long)blockIdx.z * KLEN;
  float* outf = part + (long)blockIdx.z * 4194304;
  const int f = blockIdx.x + 8 * blockIdx.y;           // 0..255
  const int grp = f >> 5, r = f & 31;                  // 8 bn x 4 bm groups
  const int bnt = r & 7, bmt = grp * 4 + (r >> 3);
  GEMM_CORE(A, Bw, KLEN, KSTRIDE, bmt, bnt)
#pragma unroll
  for (int i = 0; i < 4; ++i) {
    const long row0 = bm + wm + i * 16 + fq * 4;
#pragma unroll
    for (int j = 0; j < 4; ++j) {
      const long col = bn + wn + j * 16 + fr;
#pragma unroll
      for (int r2 = 0; r2 < 4; ++r2)
        outf[(row0 + r2) * 1024 + col] = acc[i][j][r2];
    }
  }
}

// d_out = part0 + part1 + fc2_b + x2   (one block per token row)
__global__ __launch_bounds__(256)
void fc2red_k(const float* __restrict__ part, const float* __restrict__ x2,
              const float* __restrict__ fc2_b, float* __restrict__ out)
{
  const long row = blockIdx.x;
  const int tid = threadIdx.x;
  const long idx = row * 1024 + tid * 4;
  const float4 p0 = *(const float4*)&part[idx];
  const float4 p1 = *(const float4*)&part[idx + 4194304];
  const float4 xv = *(const float4*)&x2[idx];
  const float4 bv = *(const float4*)&fc2_b[tid * 4];
  float4 o;
  o.x = p0.x + p1.x + xv.x + bv.x;
  o.y = p0.y + p1.y + xv.y + bv.y;
  o.z = p0.z + p1.z + xv.z + bv.z;
  o.w = p0.w + p1.w + xv.w + bv.w;
  *(float4*)&out[idx] = o;
}

// Fused h-projections: N=4480 stacked [qkv(3072) | w4(384) | memv(1024)].
// Grid (35,32). Swizzle: groups of 7 bn x 32 bm -> demand A 5x8MB + B 9MB
// (vs unswizzled 35x8MB A re-fetch). q scaled by DH^-0.5; v TRANSPOSED.
__global__ __launch_bounds__(256, 4)
void gemm3_k(const bf16* __restrict__ A, const bf16* __restrict__ Bw,
             const float* __restrict__ qkv_b, const float* __restrict__ memv_b,
             bf16* __restrict__ qk_out /*q|k at [B,H,T,64]*/,
             bf16* __restrict__ vt_out /*[B,H,64,T]*/,
             float* __restrict__ w4out /*[4096,384]*/,
             float* __restrict__ memval /*[B,T,D]*/)
{
  const int f = blockIdx.x + 35 * blockIdx.y;          // 0..1119
  const int grp = f / 224, r = f % 224;                // 7 bn x 32 bm groups
  const int bnt = grp * 7 + r % 7, bmt = r / 7;
  GEMM_CORE(A, Bw, 1024, 1024, bmt, bnt)
  if (bn < 3072) {
#pragma unroll
    for (int i = 0; i < 4; ++i) {
      const long row0 = bm + wm + i * 16 + fq * 4;
      const long b = row0 >> 10, t0 = row0 & 1023;
#pragma unroll
      for (int j = 0; j < 4; ++j) {
        const long col = bn + wn + j * 16 + fr;
        const long i3 = col >> 10;          // 0=q 1=k 2=v (uniform per j)
        const long hh = (col >> 6) & 15;
        const long d  = col & 63;
        const float bs = qkv_b[col];
        if (i3 == 2) {                      // v -> transposed, vectorize over t
          bf16x4 y;
#pragma unroll
          for (int r2 = 0; r2 < 4; ++r2) y[r2] = (bf16)(acc[i][j][r2] + bs);
          *(bf16x4*)&vt_out[((b * 16 + hh) * 64 + d) * 1024 + t0] = y;
        } else {
          const float sc2 = (i3 == 0) ? 0.125f : 1.0f;
          const long base = i3 * 4194304 + ((b * 16 + hh) * 1024 + t0) * 64 + d;
#pragma unroll
          for (int r2 = 0; r2 < 4; ++r2)
            qk_out[base + r2 * 64] = (bf16)((acc[i][j][r2] + bs) * sc2);
        }
      }
    }
  } else if (bn < 3456) {
#pragma unroll
    for (int i = 0; i < 4; ++i) {
      const long row0 = bm + wm + i * 16 + fq * 4;
#pragma unroll
      for (int j = 0; j < 4; ++j) {
        const long col = bn + wn + j * 16 + fr - 3072;
#pragma unroll
        for (int r2 = 0; r2 < 4; ++r2)
          w4out[(row0 + r2) * 384 + col] = acc[i][j][r2];
      }
    }
  } else {
#pragma unroll
    for (int i = 0; i < 4; ++i) {
      const long row0 = bm + wm + i * 16 + fq * 4;
#pragma unroll
      for (int j = 0; j < 4; ++j) {
        const long col = bn + wn + j * 16 + fr - 3456;
        const float bs = memv_b[col];
#pragma unroll
        for (int r2 = 0; r2 < 4; ++r2)
          memval[(row0 + r2) * 1024 + col] = acc[i][j][r2] + bs;
      }
    }
  }
}

// ---------------------------------------------------------------------------
// Flash-style causal attention + fused memory-branch combine. Block bx
// handles q-tiles {bx, 15-bx} -> every block does 17 k-tile iterations.
// Epilogue: comb = bf16(softmax(QK)V + g * memval), g precomputed per row.
// ---------------------------------------------------------------------------
__global__ __launch_bounds__(256, 3)
void attn_k(const bf16* __restrict__ q, const bf16* __restrict__ k,
            const bf16* __restrict__ vt, const float* __restrict__ memval,
            const float* __restrict__ gbuf, bf16* __restrict__ comb)
{
  __shared__ __align__(16) bf16 Ks[64 * 72];
  __shared__ __align__(16) bf16 Vs[64 * 72];
  __shared__ __align__(16) bf16 Ps[4][16 * 72];
  const int bx = blockIdx.x, h = blockIdx.y, b = blockIdx.z;
  const int tid = threadIdx.x;
  const int wave = tid >> 6, lane = tid & 63;
  const int fr = lane & 15, fq = lane >> 4;
  const long bh  = ((long)b * 16 + h) * 1024;   // q/k row base
  const long bhv = ((long)b * 16 + h) * 64;     // vt row base

  for (int pass = 0; pass < 2; ++pass) {
    const int qt = pass ? 15 - bx : bx;
    const int qbase = qt * 64;
    const bf16x8 aq0 = *(const bf16x8*)&q[(bh + qbase + wave * 16 + fr) * 64 + fq * 8];
    const bf16x8 aq1 = *(const bf16x8*)&q[(bh + qbase + wave * 16 + fr) * 64 + 32 + fq * 8];

    f32x4 o[4] = {};
    float m_r[4] = {-1e30f, -1e30f, -1e30f, -1e30f};
    float l_r[4] = {0.0f, 0.0f, 0.0f, 0.0f};

    for (int kt = 0; kt <= qt; ++kt) {
      const int kb = kt * 64;
      __syncthreads();                           // protect LDS reuse
#pragma unroll
      for (int rep = 0; rep < 2; ++rep) {        // stage K tile
        const int c = rep * 256 + tid;           // 512 x 16B chunks
        const int key = c >> 3, seg = c & 7;
        *(bf16x8*)&Ks[key * 72 + seg * 8] =
            *(const bf16x8*)&k[(bh + kb + key) * 64 + seg * 8];
      }
#pragma unroll
      for (int rep = 0; rep < 2; ++rep) {        // stage V^T tile (row d)
        const int c = rep * 256 + tid;
        const int d = c >> 3, seg = c & 7;
        *(bf16x8*)&Vs[d * 72 + seg * 8] =
            *(const bf16x8*)&vt[(bhv + d) * 1024 + kb + seg * 8];
      }
      __syncthreads();

      // S = Q K^T (16 q-rows per wave x 64 keys)
      f32x4 s[4];
#pragma unroll
      for (int j = 0; j < 4; ++j) {
        const bf16x8 b0 = *(const bf16x8*)&Ks[(j * 16 + fr) * 72 + fq * 8];
        const bf16x8 b1 = *(const bf16x8*)&Ks[(j * 16 + fr) * 72 + 32 + fq * 8];
        f32x4 tacc = {};
        tacc = mfma16(aq0, b0, tacc);
        tacc = mfma16(aq1, b1, tacc);
        s[j] = tacc;
      }
      if (kt == qt) {                            // causal mask, diagonal tile
#pragma unroll
        for (int j = 0; j < 4; ++j)
#pragma unroll
          for (int r = 0; r < 4; ++r)
            if (kb + j * 16 + fr > qbase + wave * 16 + fq * 4 + r) s[j][r] = -1e30f;
      }

      // online softmax per q-row (rows live on 16-lane groups)
      float alpha[4];
#pragma unroll
      for (int r = 0; r < 4; ++r) {
        float t = fmaxf(fmaxf(s[0][r], s[1][r]), fmaxf(s[2][r], s[3][r]));
#pragma unroll
        for (int off = 1; off < 16; off <<= 1) t = fmaxf(t, __shfl_xor(t, off));
        const float mn = fmaxf(m_r[r], t);
        alpha[r] = __expf(m_r[r] - mn);
        m_r[r] = mn;
        float ls = 0.0f;
#pragma unroll
        for (int j = 0; j < 4; ++j) {
          const float p = __expf(s[j][r] - mn);
          s[j][r] = p;
          ls += p;
        }
#pragma unroll
        for (int off = 1; off < 16; off <<= 1) ls += __shfl_xor(ls, off);
        l_r[r] = l_r[r] * alpha[r] + ls;
#pragma unroll
        for (int jd = 0; jd < 4; ++jd) o[jd][r] *= alpha[r];
      }

      // P: C/D layout -> A-operand layout via per-wave LDS
#pragma unroll
      for (int j = 0; j < 4; ++j)
#pragma unroll
        for (int r = 0; r < 4; ++r)
          Ps[wave][(fq * 4 + r) * 72 + j * 16 + fr] = (bf16)s[j][r];

      const bf16x8 ap0 = *(const bf16x8*)&Ps[wave][fr * 72 + fq * 8];
      const bf16x8 ap1 = *(const bf16x8*)&Ps[wave][fr * 72 + 32 + fq * 8];
#pragma unroll
      for (int jd = 0; jd < 4; ++jd) {
        const bf16x8 b0 = *(const bf16x8*)&Vs[(jd * 16 + fr) * 72 + fq * 8];
        const bf16x8 b1 = *(const bf16x8*)&Vs[(jd * 16 + fr) * 72 + 32 + fq * 8];
        o[jd] = mfma16(ap0, b0, o[jd]);
        o[jd] = mfma16(ap1, b1, o[jd]);
      }
    }

#pragma unroll
    for (int r = 0; r < 4; ++r) {
      const long t_ = qbase + wave * 16 + fq * 4 + r;
      const long row = (long)b * 1024 + t_;
      const float inv = 1.0f / l_r[r];
      const float gv = gbuf[row];
#pragma unroll
      for (int jd = 0; jd < 4; ++jd) {
        const long col = h * 64 + jd * 16 + fr;
        comb[row * 1024 + col] =
            (bf16)(o[jd][r] * inv + gv * memval[row * 1024 + col]);
      }
    }
  }
}

// ---------------------------------------------------------------------------
// Plücker exterior (used inline by memscore).
// ---------------------------------------------------------------------------
DEV void ext6(const float* p1, const float* p2, float* out) {
  const float L0 = p1[0] * p2[1] - p1[1] * p2[0];
  const float L1 = p1[0] * p2[2] - p1[2] * p2[0];
  const float L2 = p1[0] * p2[3] - p1[3] * p2[0];
  const float L3 = p1[1] * p2[2] - p1[2] * p2[1];
  const float L4 = p1[1] * p2[3] - p1[3] * p2[1];
  const float L5 = p1[2] * p2[3] - p1[3] * p2[2];
  const float nrm = sqrtf(L0*L0 + L1*L1 + L2*L2 + L3*L3 + L4*L4 + L5*L5);
  const float inv = 1.0f / fmaxf(nrm, 1e-12f);
  out[0] = L0 * inv; out[1] = L1 * inv; out[2] = L2 * inv;
  out[3] = L3 * inv; out[4] = L4 * inv; out[5] = L5 * inv;
}

// ---------------------------------------------------------------------------
// mem_score[b,h,i] = sum_{j<i} |dot6(rl_i, jw_j)| * d^(i-j), chunked over j.
// Lines computed INLINE from w4out. Grid (10,64): lower-triangle
// (i-tile, j-chunk) pairs; atomicAdd partials into pre-zeroed ms.
// ---------------------------------------------------------------------------
__global__ __launch_bounds__(256)
void memscore_k(const float* __restrict__ w4o,
                const float* __restrict__ decay_logits, float* __restrict__ ms)
{
  __shared__ __align__(16) float jwS[256 * 8];
  const int IT[10] = {0,1,1,2,2,2,3,3,3,3};
  const int JC[10] = {0,0,1,0,1,2,0,1,2,3};
  const int it = IT[blockIdx.x], jc = JC[blockIdx.x];
  const int bh = blockIdx.y, hh = bh & 15, b = bh >> 4;
  const float d = sigf(decay_logits[hh]);
  const float invd = 1.0f / d;
  const int j0 = jc * 256;
  {  // stage jw rows [j0, j0+256): write line = J6 * ext(w1_prev, w2_cur)
    const int j = j0 + threadIdx.x;
    const long nj = (long)b * 1024 + j;
    float p1[4], p2[4], wl[6];
    if (j == 0) { p1[0] = p1[1] = p1[2] = p1[3] = 0.0f; }
    else {
      const float* s = w4o + (nj - 1) * 384 + hh * 4;
      p1[0] = s[0]; p1[1] = s[1]; p1[2] = s[2]; p1[3] = s[3];
    }
    { const float* s = w4o + nj * 384 + 64 + hh * 4;
      p2[0] = s[0]; p2[1] = s[1]; p2[2] = s[2]; p2[3] = s[3]; }
    ext6(p1, p2, wl);
    float* dstS = &jwS[threadIdx.x * 8];
    dstS[0] =  wl[5]; dstS[1] = -wl[4]; dstS[2] =  wl[3];
    dstS[3] =  wl[2]; dstS[4] = -wl[1]; dstS[5] =  wl[0];
    dstS[6] = 0.0f;   dstS[7] = 0.0f;
  }
  __syncthreads();
  const int i = it * 256 + threadIdx.x;
  const long ni = (long)b * 1024 + i;
  float q1[4], q2[4], rv[6];
  { const float* s = w4o + ni * 384 + 128 + hh * 4;
    q1[0] = s[0]; q1[1] = s[1]; q1[2] = s[2]; q1[3] = s[3]; }
  { const float* s = w4o + ni * 384 + 192 + hh * 4;
    q2[0] = s[0]; q2[1] = s[1]; q2[2] = s[2]; q2[3] = s[3]; }
  ext6(q1, q2, rv);
  const int nj = (jc == it) ? (int)threadIdx.x : 256;   // j < i
  float w = __expf(__logf(d) * (float)(i - j0));        // d^(i-j0)
  float s = 0.0f;
  for (int jj = 0; jj < nj; ++jj) {
    const float* row = &jwS[jj * 8];
    const float dot = rv[0] * row[0] + rv[1] * row[1] + rv[2] * row[2] +
                      rv[3] * row[3] + rv[4] * row[4] + rv[5] * row[5];
    s += fabsf(dot) * w;
    w *= invd;
  }
  atomicAdd(&ms[(long)bh * 1024 + i], s);
}

// ---------------------------------------------------------------------------
// g[b,t] = mean_h sigmoid(ms*scale) * sigmoid(memg + memg_b)
// ---------------------------------------------------------------------------
__global__ __launch_bounds__(256)
void gate_k(const float* __restrict__ w4o, const float* __restrict__ ms,
            const float* __restrict__ memg_b, const float* __restrict__ mem_scale,
            float* __restrict__ g)
{
  const int n = blockIdx.x * 256 + threadIdx.x;   // b*1024 + t
  const int b = n >> 10, t = n & 1023;
  float acc = 0.0f;
#pragma unroll
  for (int h = 0; h < 16; ++h) {
    const float gate = sigf(w4o[(long)n * 384 + 256 + h] + memg_b[h]);
    acc += sigf(ms[((long)(b * 16 + h)) * 1024 + t] * mem_scale[h]) * gate;
  }
  g[n] = acc * (1.0f / 16.0f);
}

// ---------------------------------------------------------------------------
extern "C" void kernel_launch(void* const* d_in, const int* in_sizes, int n_in,
                              void* d_out, int out_size, void* d_ws, size_t ws_size,
                              hipStream_t stream) {
  (void)in_sizes; (void)n_in; (void)out_size; (void)ws_size;
  const float* x         = (const float*)d_in[0];
  const float* ln1_g     = (const float*)d_in[1];
  const float* ln1_b     = (const float*)d_in[2];
  const float* qkv_w     = (const float*)d_in[3];
  const float* qkv_b     = (const float*)d_in[4];
  const float* w1w       = (const float*)d_in[5];
  const float* w2w       = (const float*)d_in[6];
  const float* w1r       = (const float*)d_in[7];
  const float* w2r       = (const float*)d_in[8];
  const float* memv_w    = (const float*)d_in[9];
  const float* memv_b    = (const float*)d_in[10];
  const float* memg_w    = (const float*)d_in[11];
  const float* memg_b    = (const float*)d_in[12];
  const float* mem_scale = (const float*)d_in[13];
  const float* out_w     = (const float*)d_in[14];
  const float* out_b     = (const float*)d_in[15];
  const float* decay_l   = (const float*)d_in[16];
  const float* ln2_g     = (const float*)d_in[17];
  const float* ln2_b     = (const float*)d_in[18];
  const float* fc1_w     = (const float*)d_in[19];
  const float* fc1_b     = (const float*)d_in[20];
  const float* fc2_w     = (const float*)d_in[21];
  const float* fc2_b     = (const float*)d_in[22];

  char* ws = (char*)d_ws;
  bf16*  Wbf    = (bf16*)ws;                       // stacked bf16 weights (28 MB)
  bf16*  Wout   = Wbf + 4587520;
  bf16*  Wfc1   = Wbf + 5636096;
  bf16*  Wfc2   = Wbf + 9830400;
  bf16*  h_bf   = (bf16*)(ws + 28049408);          // 8 MB (h, then h2)
  bf16*  q_bf   = (bf16*)(ws + 36438016);          // q|k|vt, 8 MB each
  bf16*  vt_bf  = q_bf + 2 * 4194304;
  // outproj partials (2x16 MB) overlay dead q/k/vt after attention
  float* oppart = (float*)(ws + 36438016);
  bf16*  fc1out = q_bf;                            // 32 MB, after ln2red
  float* w4out  = (float*)(ws + 78381056);         // [4096,384] f32 (6.3 MB)
  float* msb    = (float*)(ws + 84672512);         // [64,1024] f32
  float* gbuf   = (float*)(ws + 84934656);         // [4096] f32
  float* memval = (float*)(ws + 88080384);         // 16 MB
  // FC2 partials (2x16 MB) overlay dead w4out..memval region
  float* fc2part = (float*)(ws + 69992448);        // 69992448..103546880
  bf16*  comb   = (bf16*)(ws + 104857600);         // 8 MB
  float* x2     = (float*)(ws + 113246208);        // 16 MB

  // 1) weight cast (vectorized x4)
  cast_w_k<<<13696, 256, 0, stream>>>(qkv_w, w1w, w2w, w1r, w2r, memg_w,
                                      memv_w, out_w, fc1_w, fc2_w, Wbf);
  // 2) LN1
  ln_k<<<4096, 256, 0, stream>>>(x, ln1_g, ln1_b, h_bf);
  // 3) fused QKV + W4 + memv GEMM (N=4480, swizzled)
  gemm3_k<<<dim3(35, 32), 256, 0, stream>>>(h_bf, Wbf, qkv_b, memv_b,
                                            q_bf, vt_bf, w4out, memval);
  // 4) incidence x decay reduction (lines inlined; chunked + atomic)
  hipMemsetAsync(msb, 0, 64 * 1024 * sizeof(float), stream);
  memscore_k<<<dim3(10, 64), 256, 0, stream>>>(w4out, decay_l, msb);
  // 5) per-row gate mean
  gate_k<<<16, 256, 0, stream>>>(w4out, msb, memg_b, mem_scale, gbuf);
  // 6) causal attention + fused combine -> comb (bf16)
  attn_k<<<dim3(8, 16, 4), 256, 0, stream>>>(q_bf, q_bf + 4194304, vt_bf,
                                             memval, gbuf, comb);
  // 7) out-proj split-K=2 -> partials (q/k/vt dead)
  gemm_splitk_k<512, 1024><<<dim3(8, 32, 2), 256, 0, stream>>>(comb, Wout,
                                                               oppart);
  // 8) reduce + bias + residual(x) -> x2, then LN2 -> h_bf
  ln2red_k<<<4096, 256, 0, stream>>>(oppart, out_b, x, ln2_g, ln2_b, x2, h_bf);
  // 9) FC1 + GELU(exact)  (overwrites oppart region)
  gemm_k<M_GELU, 1024><<<dim3(32, 32), 256, 0, stream>>>(h_bf, Wfc1, 4096,
                                                   fc1_b, nullptr, nullptr, fc1out);
  // 10) FC2 split-K=2 -> partials
  gemm_splitk_k<2048, 4096><<<dim3(8, 32, 2), 256, 0, stream>>>(fc1out, Wfc2,
                                                                fc2part);
  // 11) reduce partials + bias + residual(x2) -> d_out
  fc2red_k<<<4096, 256, 0, stream>>>(fc2part, x2, fc2_b, (float*)d_out);
}